// Round 2
// baseline (175.400 us; speedup 1.0000x reference)
//
#include <hip/hip_runtime.h>

// Problem constants (from reference)
constexpr int kB    = 16384;    // batch
constexpr int kNeg  = 10;       // negatives per example
constexpr int kE    = 128;      // embedding dim
constexpr int kV    = 100000;   // vocab
constexpr int kCap  = 32;       // bucket capacity per word. Occurrences/word ~ Poisson(1.8)
                                // (163840 noise + 16384 ctx draws over 100k words); max for
                                // the fixed seed-0 input is ~13. 32 is bulletproof.
constexpr int kPairs      = kB * (kNeg + 1);   // 180224 = 704 * 256 exactly
constexpr int kMainBlocks = kV / 8;            // 12500: 8 words per 256-thread block

// Workspace layout (ints/floats, 4B elements; ws is 256 MiB, we use ~14 MB):
//   cnt      : kV ints            [word occurrence counters]
//   bucket   : kV*kCap ints       [packed occurrences: iw | (isNoise<<31)]
//   partials : kMainBlocks floats

__device__ __forceinline__ float log_sigmoid(float x) {
    // numerically stable: min(x,0) - log1p(exp(-|x|))
    return fminf(x, 0.0f) - log1pf(expf(-fabsf(x)));
}

__device__ __forceinline__ float dot4(float4 a, float4 b) {
    return a.x * b.x + a.y * b.y + a.z * b.z + a.w * b.w;
}

// --- 1. zero the per-word counters (ws is poisoned every iteration) ---------
__global__ __launch_bounds__(256) void w2v_zero_counts(int* __restrict__ cnt)
{
    const int i = blockIdx.x * 256 + threadIdx.x;
    if (i < kV) cnt[i] = 0;
}

// --- 2. build inverted index: word -> list of (center-row, sign) ------------
// Pair i<kB: positive pair (w=context_word[i], center=input_word[i], sign +).
// Pair i>=kB: noise pair j=i-kB (w=noise_words[j], center=input_word[j/10], sign -).
__global__ __launch_bounds__(256) void w2v_build_index(
    const int* __restrict__ input_word,
    const int* __restrict__ context_word,
    const int* __restrict__ noise_words,
    int*       __restrict__ cnt,
    int*       __restrict__ bucket)
{
    const int i = blockIdx.x * 256 + threadIdx.x;   // grid sized exactly kPairs
    int w, payload;
    if (i < kB) {
        w = context_word[i];
        payload = input_word[i];                    // sign bit 0 => positive pair
    } else {
        const int j = i - kB;
        w = noise_words[j];
        payload = input_word[j / kNeg] | (int)0x80000000;  // sign bit 1 => noise
    }
    const int slot = atomicAdd(&cnt[w], 1);
    if (slot < kCap) bucket[w * kCap + slot] = payload;
}

// --- 3. main pass: stream W_ctx sequentially, gather centers from L3 --------
// One word per 32-lane half-wave; 8 words per block; words in order =>
// W_ctx reads are perfectly sequential across the grid (51.2 MB read once).
// W_in center rows: 16384 unique rows (8.4 MB footprint) reused ~11x each —
// first touch from HBM, reuse served by the 256 MiB L3.
__global__ __launch_bounds__(256, 8) void w2v_main(
    const float* __restrict__ W_in,
    const float* __restrict__ W_ctx,
    const int*   __restrict__ cnt,
    const int*   __restrict__ bucket,
    float*       __restrict__ partials)
{
    const int tid  = threadIdx.x;
    const int wave = tid >> 6;
    const int lane = tid & 63;
    const int half = lane >> 5;
    const int l32  = lane & 31;

    const int word = blockIdx.x * 8 + wave * 2 + half;   // < kV always (kV % 8 == 0)

    int c = cnt[word];
    c = c < kCap ? c : kCap;      // safety clamp (never hit for this input)

    float s = 0.0f;
    if (c > 0) {
        // 512B contiguous row; two halves of the wave read adjacent words ->
        // each instruction covers 1KB contiguous, sequential across blocks.
        const float4 row = ((const float4*)(W_ctx + (size_t)word * kE))[l32];
        for (int j = 0; j < c; ++j) {
            const int e  = bucket[word * kCap + j];      // broadcast load (L1)
            const int iw = e & 0x7FFFFFFF;
            const float4 cv = ((const float4*)(W_in + (size_t)iw * kE))[l32];
            float d = dot4(row, cv);
            #pragma unroll
            for (int off = 16; off > 0; off >>= 1)
                d += __shfl_xor(d, off);                 // stays within the half
            const float term = log_sigmoid(e < 0 ? -d : d);
            if (l32 == 0) s += term;
        }
    }

    __shared__ float smem[8];
    if (l32 == 0) smem[wave * 2 + half] = s;             // all halves write (s=0 if c==0)
    __syncthreads();
    if (tid == 0) {
        float t = 0.0f;
        #pragma unroll
        for (int k = 0; k < 8; ++k) t += smem[k];
        partials[blockIdx.x] = t;
    }
}

// --- 4. final reduction ------------------------------------------------------
__global__ __launch_bounds__(256) void w2v_reduce_kernel(
    const float* __restrict__ partials,
    float*       __restrict__ out)
{
    float acc = 0.0f;
    for (int i = threadIdx.x; i < kMainBlocks; i += 256)
        acc += partials[i];

    #pragma unroll
    for (int off = 32; off > 0; off >>= 1)
        acc += __shfl_xor(acc, off);

    __shared__ float smem[4];
    const int lane = threadIdx.x & 63;
    const int wave = threadIdx.x >> 6;
    if (lane == 0) smem[wave] = acc;
    __syncthreads();
    if (threadIdx.x == 0) {
        const float total = smem[0] + smem[1] + smem[2] + smem[3];
        out[0] = -total / (float)kB;
    }
}

extern "C" void kernel_launch(void* const* d_in, const int* in_sizes, int n_in,
                              void* d_out, int out_size, void* d_ws, size_t ws_size,
                              hipStream_t stream) {
    const int*   input_word   = (const int*)d_in[0];
    const int*   context_word = (const int*)d_in[1];
    const int*   noise_words  = (const int*)d_in[2];
    const float* W_in         = (const float*)d_in[3];
    const float* W_ctx        = (const float*)d_in[4];
    float*       out          = (float*)d_out;

    int*   cnt      = (int*)d_ws;
    int*   bucket   = cnt + kV;
    float* partials = (float*)(bucket + (size_t)kV * kCap);

    w2v_zero_counts<<<(kV + 255) / 256, 256, 0, stream>>>(cnt);
    w2v_build_index<<<kPairs / 256, 256, 0, stream>>>(
        input_word, context_word, noise_words, cnt, bucket);
    w2v_main<<<kMainBlocks, 256, 0, stream>>>(W_in, W_ctx, cnt, bucket, partials);
    w2v_reduce_kernel<<<1, 256, 0, stream>>>(partials, out);
}